// Round 7
// baseline (150.674 us; speedup 1.0000x reference)
//
#include <hip/hip_runtime.h>

#define MAXS 512
#define SEG 4096      // points per segment (16 per thread)
#define BLK 256       // 4 waves
#define SMAX 64       // max segments per batch (S=49)

// Single-launch "last block done" structure. Zero polling (R3/R4 lesson:
// polled agent-scope acquires thrash L1/L2 chip-wide; one-shot release/
// acquire atomics are fine and were proven correct in R4).
// Phase A (all 784 blocks): classify own segment, store 8 counts + per-thread
//   packed nibble word (member<<3|oct per point), one atomicAdd on done[b].
// Phase B (the unique last arriver per batch): walk segments in order with
//   early-exit once all octants are full (~6/49 for this data), rebuilding
//   stable ranks from the 2 KB/segment nibble records (L2-hit), scatter, and
//   back-fill -1 tails from grand totals.
__global__ __launch_bounds__(BLK) void octant_lastblock_kernel(
    const float* __restrict__ pcs, int* __restrict__ out,
    unsigned* __restrict__ done, unsigned* __restrict__ counts,
    unsigned long long* __restrict__ nibs, int N, int S) {
  const int bs = blockIdx.x;
  const int b = bs / S, s = bs - b * S;
  const int tid = threadIdx.x;
  const int wid = tid >> 6, lane = tid & 63;

  const float* __restrict__ xp = pcs + (size_t)b * 3 * N;
  const float* __restrict__ yp = xp + N;
  const float* __restrict__ zp = yp + N;
  int* __restrict__ ob = out + (size_t)b * 8 * MAXS;

  __shared__ unsigned long long sW[BLK / 64][2];
  __shared__ unsigned sCnt[SMAX][8];
  __shared__ unsigned sBase[8], sTot[8];
  __shared__ int sFin;

  // ---------------- Phase A: classify own segment ----------------
  unsigned long long mo = 0ull;                 // 16 packed nibbles
  unsigned long long clo = 0ull, chi = 0ull;    // u16 fields: oct 0..3 / 4..7
  const int tb = s * SEG + tid * 16;
  #pragma unroll
  for (int jj = 0; jj < 4; ++jj) {
    const int g = tb + jj * 4;
    float xv[4], yv[4], zv[4];
    if (g + 4 <= N) {  // N%4==0: a float4 is fully in or fully out
      const float4 x4 = *(const float4*)(xp + g);
      const float4 y4 = *(const float4*)(yp + g);
      const float4 z4 = *(const float4*)(zp + g);
      xv[0] = x4.x; xv[1] = x4.y; xv[2] = x4.z; xv[3] = x4.w;
      yv[0] = y4.x; yv[1] = y4.y; yv[2] = y4.z; yv[3] = y4.w;
      zv[0] = z4.x; zv[1] = z4.y; zv[2] = z4.z; zv[3] = z4.w;
    } else {
      #pragma unroll
      for (int p = 0; p < 4; ++p) { xv[p] = 2.0f; yv[p] = 2.0f; zv[p] = 2.0f; }
    }
    #pragma unroll
    for (int p = 0; p < 4; ++p) {
      // per-op IEEE f32 rounding matches numpy (no FMA at the r2~1 boundary)
      const float r2 = __fadd_rn(
          __fadd_rn(__fmul_rn(xv[p], xv[p]), __fmul_rn(yv[p], yv[p])),
          __fmul_rn(zv[p], zv[p]));
      const bool member = (r2 <= 1.0f);
      const unsigned oct = ((xv[p] >= 0.f) ? 4u : 0u) |
                           ((yv[p] >= 0.f) ? 2u : 0u) |
                           ((zv[p] >= 0.f) ? 1u : 0u);
      mo |= ((unsigned long long)((member ? 8u : 0u) | oct))
            << (4 * (jj * 4 + p));
      const unsigned long long inc = 1ull << ((oct & 3u) * 16u);
      clo += (member && oct < 4u) ? inc : 0ull;
      chi += (member && oct >= 4u) ? inc : 0ull;
    }
  }
  // block totals via butterfly (fields <= 4096 < 65536)
  #pragma unroll
  for (int d = 1; d < 64; d <<= 1) {
    clo += __shfl_xor(clo, d, 64);
    chi += __shfl_xor(chi, d, 64);
  }
  if (lane == 0) { sW[wid][0] = clo; sW[wid][1] = chi; }
  __syncthreads();
  if (tid < 8) {
    unsigned t = 0;
    #pragma unroll
    for (int w = 0; w < BLK / 64; ++w)
      t += (unsigned)((sW[w][tid >> 2] >> ((tid & 3) * 16)) & 0xffffull);
    counts[(size_t)bs * 8 + tid] = t;
  }
  nibs[(size_t)bs * BLK + tid] = mo;

  // ---------------- arrival: one release-add, zero polling ----------------
  __threadfence();   // all threads: order own stores before the arrival
  __syncthreads();
  if (tid == 0) {
    const unsigned old = __hip_atomic_fetch_add(
        done + b, 1u, __ATOMIC_ACQ_REL, __HIP_MEMORY_SCOPE_AGENT);
    sFin = (old == (unsigned)(S - 1)) ? 1 : 0;
  }
  __syncthreads();
  if (!sFin) return;  // 768 of 784 blocks exit here

  // ---------------- Phase B: unique finisher for batch b ----------------
  for (int i = tid; i < S * 8; i += BLK)
    sCnt[i >> 3][i & 7] = counts[(size_t)b * S * 8 + i];
  __syncthreads();
  if (tid < 8) {
    unsigned t = 0;
    for (int s2 = 0; s2 < S; ++s2) t += sCnt[s2][tid];
    sTot[tid] = t;
    sBase[tid] = 0;
  }
  __syncthreads();

  for (int s2 = 0; s2 < S; ++s2) {
    if (sBase[0] >= MAXS && sBase[1] >= MAXS && sBase[2] >= MAXS &&
        sBase[3] >= MAXS && sBase[4] >= MAXS && sBase[5] >= MAXS &&
        sBase[6] >= MAXS && sBase[7] >= MAXS)
      break;  // all octants full: no later segment contributes

    const unsigned long long w =
        nibs[((size_t)(b * S + s2)) * BLK + tid];  // 2 KB, L2-hit
    unsigned long long plo = 0ull, phi = 0ull;
    #pragma unroll
    for (int p = 0; p < 16; ++p) {
      const unsigned nib = (unsigned)((w >> (4 * p)) & 15ull);
      const bool member = (nib & 8u) != 0u;
      const unsigned oct = nib & 7u;
      const unsigned long long inc = 1ull << ((oct & 3u) * 16u);
      plo += (member && oct < 4u) ? inc : 0ull;
      phi += (member && oct >= 4u) ? inc : 0ull;
    }
    unsigned long long ilo = plo, ihi = phi;  // wave inclusive scan
    #pragma unroll
    for (int d = 1; d < 64; d <<= 1) {
      const unsigned long long tl = __shfl_up(ilo, (unsigned)d, 64);
      const unsigned long long th = __shfl_up(ihi, (unsigned)d, 64);
      if (lane >= d) { ilo += tl; ihi += th; }
    }
    unsigned long long elo = ilo - plo, ehi = ihi - phi;
    if (lane == 63) { sW[wid][0] = ilo; sW[wid][1] = ihi; }
    __syncthreads();
    #pragma unroll
    for (int ww = 0; ww < BLK / 64; ++ww) {
      if (ww < wid) { elo += sW[ww][0]; ehi += sW[ww][1]; }
    }

    const int pbase = s2 * SEG + tid * 16;
    #pragma unroll
    for (int o = 0; o < 8; ++o) {
      const unsigned long long ef = (o < 4) ? elo : ehi;
      unsigned r = sBase[o] + (unsigned)((ef >> ((o & 3) * 16)) & 0xffffull);
      #pragma unroll
      for (int p = 0; p < 16; ++p) {
        const unsigned nib = (unsigned)((w >> (4 * p)) & 15ull);
        if (nib == (8u | (unsigned)o)) {
          if (r < MAXS) ob[o * MAXS + (int)r] = pbase + p;
          ++r;
        }
      }
    }
    __syncthreads();  // scatters (readers of sBase/sW) done
    if (tid < 8) sBase[tid] += sCnt[s2][tid];
    __syncthreads();  // sBase updated; sW free for next iteration
  }

  // back-fill -1 tails from grand totals (no-op slots skipped)
  for (int i = tid; i < 8 * MAXS; i += BLK) {
    const int o = i >> 9;
    const unsigned rr = (unsigned)(i & (MAXS - 1));
    const unsigned lim = sTot[o] > MAXS ? MAXS : sTot[o];
    if (rr >= lim) ob[i] = -1;
  }
}

extern "C" void kernel_launch(void* const* d_in, const int* in_sizes, int n_in,
                              void* d_out, int out_size, void* d_ws, size_t ws_size,
                              hipStream_t stream) {
  const float* pcs = (const float*)d_in[0];
  int* out = (int*)d_out;
  const int B = out_size / (8 * MAXS);   // 16
  const int N = in_sizes[0] / (3 * B);   // 200000
  const int S = (N + SEG - 1) / SEG;     // 49 (<= SMAX)

  unsigned* done = (unsigned*)d_ws;                       // B u32
  unsigned* counts = done + B;                            // B*S*8 u32
  unsigned long long* nibs =
      (unsigned long long*)(counts + (size_t)B * S * 8);  // B*S*BLK u64

  hipMemsetAsync(done, 0, (size_t)B * sizeof(unsigned), stream);
  octant_lastblock_kernel<<<B * S, BLK, 0, stream>>>(pcs, out, done, counts,
                                                     nibs, N, S);
}

// Round 8
// 47.739 us; speedup vs baseline: 3.1562x; 3.1562x over previous
//
#include <hip/hip_runtime.h>

#define MAXS 512
#define BLK 1024
#define PPT 32                 // points per thread per chunk
#define CHUNK (BLK * PPT)      // 32768 points: fills all octants w.p. 1-1e-27
#define NW (BLK / 64)          // 16 waves

// One block per batch, one kernel, ZERO cross-block communication.
// R3/R4/R7 lesson: any device-scope fence/atomic/poll pattern costs 50-100us
// on gfx950 (L2 writeback/invalidate storms). The work itself is ~microseconds,
// so 16 independent blocks beat any machine-filling scheme that needs sync.
// Chunk 1 (32768 pts) statistically fills all 8 octants (mean 816/oct, 11
// sigma above 512); later chunks exist only for exactness on arbitrary input.
__global__ __launch_bounds__(BLK) void octant_onepass_kernel(
    const float* __restrict__ pcs, int* __restrict__ out, int N) {
  const int b = blockIdx.x;
  const int tid = threadIdx.x, wid = tid >> 6, lane = tid & 63;
  const float* __restrict__ xp = pcs + (size_t)b * 3 * N;
  const float* __restrict__ yp = xp + N;
  const float* __restrict__ zp = yp + N;
  int* __restrict__ ob = out + (size_t)b * 8 * MAXS;

  __shared__ unsigned long long sW[NW][2];  // per-wave packed octant totals
  __shared__ unsigned sBase[8];             // running per-octant fill count

  for (int i = tid; i < 8 * MAXS; i += BLK) ob[i] = -1;
  if (tid < 8) sBase[tid] = 0;
  __syncthreads();

  const int nCh = (N + CHUNK - 1) / CHUNK;
  for (int k = 0; k < nCh; ++k) {
    const int tb = k * CHUNK + tid * PPT;  // this thread's 32 consecutive pts
    unsigned long long nib[PPT / 16];      // packed (member<<3|oct) nibbles
    unsigned long long clo = 0ull, chi = 0ull;  // u16 fields: oct 0..3 / 4..7
    #pragma unroll
    for (int q = 0; q < PPT / 16; ++q) {
      unsigned long long mo = 0ull;
      #pragma unroll
      for (int jj = 0; jj < 4; ++jj) {
        const int g = tb + q * 16 + jj * 4;
        float xv[4], yv[4], zv[4];
        if (g + 4 <= N) {  // N%4==0: float4 fully in or fully out
          const float4 x4 = *(const float4*)(xp + g);
          const float4 y4 = *(const float4*)(yp + g);
          const float4 z4 = *(const float4*)(zp + g);
          xv[0] = x4.x; xv[1] = x4.y; xv[2] = x4.z; xv[3] = x4.w;
          yv[0] = y4.x; yv[1] = y4.y; yv[2] = y4.z; yv[3] = y4.w;
          zv[0] = z4.x; zv[1] = z4.y; zv[2] = z4.z; zv[3] = z4.w;
        } else {
          #pragma unroll
          for (int p = 0; p < 4; ++p) { xv[p] = 2.f; yv[p] = 2.f; zv[p] = 2.f; }
        }
        #pragma unroll
        for (int p = 0; p < 4; ++p) {
          // per-op IEEE f32 rounding matches numpy (no FMA at r2~1 boundary)
          const float r2 = __fadd_rn(
              __fadd_rn(__fmul_rn(xv[p], xv[p]), __fmul_rn(yv[p], yv[p])),
              __fmul_rn(zv[p], zv[p]));
          const bool member = (r2 <= 1.0f);
          const unsigned oct = ((xv[p] >= 0.f) ? 4u : 0u) |
                               ((yv[p] >= 0.f) ? 2u : 0u) |
                               ((zv[p] >= 0.f) ? 1u : 0u);
          mo |= ((unsigned long long)((member ? 8u : 0u) | oct))
                << (4 * (jj * 4 + p));
          const unsigned long long inc = 1ull << ((oct & 3u) * 16u);
          clo += (member && oct < 4u) ? inc : 0ull;
          chi += (member && oct >= 4u) ? inc : 0ull;
        }
      }
      nib[q] = mo;
    }

    // wave inclusive scan on packed fields (max 64*32=2048 < 65536)
    unsigned long long ilo = clo, ihi = chi;
    #pragma unroll
    for (int d = 1; d < 64; d <<= 1) {
      const unsigned long long tl = __shfl_up(ilo, (unsigned)d, 64);
      const unsigned long long th = __shfl_up(ihi, (unsigned)d, 64);
      if (lane >= d) { ilo += tl; ihi += th; }
    }
    unsigned long long elo = ilo - clo, ehi = ihi - chi;
    if (lane == 63) { sW[wid][0] = ilo; sW[wid][1] = ihi; }
    __syncthreads();
    #pragma unroll
    for (int w = 0; w < NW; ++w)        // block max 32768 < 65536: no overflow
      if (w < wid) { elo += sW[w][0]; ehi += sW[w][1]; }

    // ordered scatter, one pass per octant (all nib indices compile-time)
    #pragma unroll
    for (int o = 0; o < 8; ++o) {
      const unsigned long long ef = (o < 4) ? elo : ehi;
      unsigned r = sBase[o] + (unsigned)((ef >> ((o & 3) * 16)) & 0xffffull);
      if (__all(r >= MAXS)) continue;   // whole wave past cap for this octant
      const unsigned want = 8u | (unsigned)o;
      #pragma unroll
      for (int q = 0; q < PPT / 16; ++q) {
        const unsigned long long w4 = nib[q];
        #pragma unroll
        for (int p = 0; p < 16; ++p) {
          if ((unsigned)((w4 >> (4 * p)) & 15ull) == want) {
            if (r < MAXS) ob[o * MAXS + (int)r] = tb + q * 16 + p;
            ++r;
          }
        }
      }
    }
    __syncthreads();  // all reads of sBase/sW for this chunk complete

    if (tid < 8) {
      unsigned t = 0;
      #pragma unroll
      for (int w = 0; w < NW; ++w)
        t += (unsigned)((sW[w][tid >> 2] >> ((tid & 3) * 16)) & 0xffffull);
      sBase[tid] += t;
    }
    __syncthreads();

    if (sBase[0] >= MAXS && sBase[1] >= MAXS && sBase[2] >= MAXS &&
        sBase[3] >= MAXS && sBase[4] >= MAXS && sBase[5] >= MAXS &&
        sBase[6] >= MAXS && sBase[7] >= MAXS)
      break;  // all octants full — nearly always after chunk 1
  }
}

extern "C" void kernel_launch(void* const* d_in, const int* in_sizes, int n_in,
                              void* d_out, int out_size, void* d_ws, size_t ws_size,
                              hipStream_t stream) {
  const float* pcs = (const float*)d_in[0];
  int* out = (int*)d_out;
  const int B = out_size / (8 * MAXS);   // 16
  const int N = in_sizes[0] / (3 * B);   // 200000
  octant_onepass_kernel<<<B, BLK, 0, stream>>>(pcs, out, N);
}

// Round 9
// 30.328 us; speedup vs baseline: 4.9682x; 1.5741x over previous
//
#include <hip/hip_runtime.h>

#define MAXS 512
#define TBLK 256
#define NR 4                     // float4 rounds per chunk
#define CHUNK (TBLK * 4 * NR)    // 4096 points per chunk

// One block per (batch, octant): 128 fully independent blocks, ZERO
// cross-block communication (R3/R4/R7: every device-scope sync idiom costs
// 50-150us on gfx950; R2/R5: each extra kernel boundary ~5-8us).
// Each block scans its batch's points from index 0 in chunks of 4096,
// keeps only its octant, early-exits once its 512 slots fill (~21k of 200k
// points). The 8 octant-blocks of a batch read the same leading ~250KB; 7/8
// hit L3, so HBM traffic stays ~5MB. Block owns its whole 512-slot slice:
// writes members in order + backfills -1 tail (no memset, no workspace).
__global__ __launch_bounds__(TBLK) void octant_po_kernel(
    const float* __restrict__ pcs, int* __restrict__ out, int N) {
  const int blk = blockIdx.x;
  const int b = blk >> 3;
  const unsigned o = (unsigned)(blk & 7);
  const int tid = threadIdx.x, wid = tid >> 6, lane = tid & 63;
  const float* __restrict__ xp = pcs + (size_t)b * 3 * N;
  const float* __restrict__ yp = xp + N;
  const float* __restrict__ zp = yp + N;
  int* __restrict__ ob = out + ((size_t)(b * 8) + o) * MAXS;

  __shared__ unsigned long long sW[2][4];  // [chunk parity][wave] totals

  unsigned base = 0;  // block-uniform: my octant's filled count
  const int nCh = (N + CHUNK - 1) / CHUNK;

  for (int k = 0; k < nCh; ++k) {
    const int cb = k * CHUNK;

    // ---- classify 16 points (4 rounds x float4, lane-adjacent: coalesced)
    unsigned mbits[NR];
    unsigned long long cpk = 0ull;  // packed per-round counts (u16 fields)
    #pragma unroll
    for (int j = 0; j < NR; ++j) {
      const int g = cb + j * (TBLK * 4) + tid * 4;
      float xv[4], yv[4], zv[4];
      if (g + 4 <= N) {  // N%4==0: float4 fully in or fully out
        const float4 x4 = *(const float4*)(xp + g);
        const float4 y4 = *(const float4*)(yp + g);
        const float4 z4 = *(const float4*)(zp + g);
        xv[0] = x4.x; xv[1] = x4.y; xv[2] = x4.z; xv[3] = x4.w;
        yv[0] = y4.x; yv[1] = y4.y; yv[2] = y4.z; yv[3] = y4.w;
        zv[0] = z4.x; zv[1] = z4.y; zv[2] = z4.z; zv[3] = z4.w;
      } else {
        #pragma unroll
        for (int p = 0; p < 4; ++p) { xv[p] = 2.f; yv[p] = 2.f; zv[p] = 2.f; }
      }
      unsigned m = 0;
      #pragma unroll
      for (int e = 0; e < 4; ++e) {
        // per-op IEEE f32 rounding matches numpy (no FMA at r2~1 boundary)
        const float r2 = __fadd_rn(
            __fadd_rn(__fmul_rn(xv[e], xv[e]), __fmul_rn(yv[e], yv[e])),
            __fmul_rn(zv[e], zv[e]));
        const unsigned oc = ((xv[e] >= 0.f) ? 4u : 0u) |
                            ((yv[e] >= 0.f) ? 2u : 0u) |
                            ((zv[e] >= 0.f) ? 1u : 0u);
        m |= ((r2 <= 1.0f) && (oc == o)) ? (1u << e) : 0u;
      }
      mbits[j] = m;
      cpk += (unsigned long long)__popc(m) << (16 * j);
    }

    // ---- one packed wave scan (4 rounds at once; fields <= 1024 < 65536)
    unsigned long long inc = cpk;
    #pragma unroll
    for (int d = 1; d < 64; d <<= 1) {
      const unsigned long long t = __shfl_up(inc, (unsigned)d, 64);
      if (lane >= d) inc += t;
    }
    unsigned long long exc = inc - cpk;
    if (lane == 63) sW[k & 1][wid] = inc;
    __syncthreads();  // the only barrier per chunk (LDS double-buffered)
    #pragma unroll
    for (int w = 0; w < 4; ++w)
      if (w < wid) exc += sW[k & 1][w];
    const unsigned long long tot4 =
        sW[k & 1][0] + sW[k & 1][1] + sW[k & 1][2] + sW[k & 1][3];

    // ---- ordered stores: point order = (round j, tid, elem e) == index order
    unsigned racc = 0;  // block count in earlier rounds of this chunk
    #pragma unroll
    for (int j = 0; j < NR; ++j) {
      unsigned r = base + racc + (unsigned)((exc >> (16 * j)) & 0xffffull);
      const int g = cb + j * (TBLK * 4) + tid * 4;
      const unsigned m = mbits[j];
      #pragma unroll
      for (int e = 0; e < 4; ++e) {
        if (m & (1u << e)) {
          if (r < MAXS) ob[(int)r] = g + e;
          ++r;
        }
      }
      racc += (unsigned)((tot4 >> (16 * j)) & 0xffffull);
    }
    base += racc;                 // uniform (same tot4 everywhere)
    if (base >= MAXS) break;      // my octant is full — done
  }

  // tail: unfilled slots get -1 (no-op when base >= MAXS)
  for (int i = (int)base + tid; i < MAXS; i += TBLK) ob[i] = -1;
}

extern "C" void kernel_launch(void* const* d_in, const int* in_sizes, int n_in,
                              void* d_out, int out_size, void* d_ws, size_t ws_size,
                              hipStream_t stream) {
  const float* pcs = (const float*)d_in[0];
  int* out = (int*)d_out;
  const int B = out_size / (8 * MAXS);   // 16
  const int N = in_sizes[0] / (3 * B);   // 200000
  octant_po_kernel<<<B * 8, TBLK, 0, stream>>>(pcs, out, N);
}

// Round 10
// 20.199 us; speedup vs baseline: 7.4596x; 1.5015x over previous
//
#include <hip/hip_runtime.h>

#define MAXS 512
#define TBLK 512                 // 8 waves
#define NW (TBLK / 64)
#define NR 4                     // float4 rounds per chunk
#define CHUNK (TBLK * 4 * NR)    // 8192 points per chunk

// One block per (batch, octant): 128 fully independent blocks, ZERO
// cross-block communication (R3/R4/R7: device-scope sync costs 50-150us on
// gfx950). R9 lesson: the per-chunk serial HBM round trip dominates; fix is
// depth-2 prefetch so chunk k+1's loads fly under chunk k's processing, plus
// 8 waves for more memory-level parallelism and fewer (bigger) chunks.
__global__ __launch_bounds__(TBLK) void octant_pf_kernel(
    const float* __restrict__ pcs, int* __restrict__ out, int N) {
  const int blk = blockIdx.x;
  const int b = blk >> 3;
  const unsigned o = (unsigned)(blk & 7);
  const int tid = threadIdx.x, wid = tid >> 6, lane = tid & 63;
  const float* __restrict__ xp = pcs + (size_t)b * 3 * N;
  const float* __restrict__ yp = xp + N;
  const float* __restrict__ zp = yp + N;
  int* __restrict__ ob = out + ((size_t)(b * 8) + o) * MAXS;

  __shared__ unsigned long long sW[2][NW];  // [chunk parity][wave] totals

  const int nCh = (N + CHUNK - 1) / CHUNK;

  float4 curx[NR], cury[NR], curz[NR];
  float4 nxtx[NR], nxty[NR], nxtz[NR];

  // Predicated load of chunk K round j (sentinel 2.0f: never a member).
  #define LOADR(K, j, DX, DY, DZ)                                     \
    do {                                                              \
      const int _g = (K) * CHUNK + (j) * (TBLK * 4) + tid * 4;        \
      if ((K) < nCh && _g + 4 <= N) {  /* N%4==0 */                   \
        DX = *(const float4*)(xp + _g);                               \
        DY = *(const float4*)(yp + _g);                               \
        DZ = *(const float4*)(zp + _g);                               \
      } else {                                                        \
        DX = make_float4(2.f, 2.f, 2.f, 2.f);                         \
        DY = DX; DZ = DX;                                             \
      }                                                               \
    } while (0)

  #pragma unroll
  for (int j = 0; j < NR; ++j) LOADR(0, j, curx[j], cury[j], curz[j]);

  unsigned base = 0;  // block-uniform: my octant's filled count

  for (int k = 0; k < nCh; ++k) {
    // ---- prefetch chunk k+1 (in flight during all processing below) ----
    #pragma unroll
    for (int j = 0; j < NR; ++j) LOADR(k + 1, j, nxtx[j], nxty[j], nxtz[j]);

    // ---- classify current chunk ----
    unsigned mbits[NR];
    unsigned long long cpk = 0ull;  // packed per-round counts (u16 fields)
    #pragma unroll
    for (int j = 0; j < NR; ++j) {
      float xv[4], yv[4], zv[4];
      xv[0] = curx[j].x; xv[1] = curx[j].y; xv[2] = curx[j].z; xv[3] = curx[j].w;
      yv[0] = cury[j].x; yv[1] = cury[j].y; yv[2] = cury[j].z; yv[3] = cury[j].w;
      zv[0] = curz[j].x; zv[1] = curz[j].y; zv[2] = curz[j].z; zv[3] = curz[j].w;
      unsigned m = 0;
      #pragma unroll
      for (int e = 0; e < 4; ++e) {
        // per-op IEEE f32 rounding matches numpy (no FMA at r2~1 boundary)
        const float r2 = __fadd_rn(
            __fadd_rn(__fmul_rn(xv[e], xv[e]), __fmul_rn(yv[e], yv[e])),
            __fmul_rn(zv[e], zv[e]));
        const unsigned oc = ((xv[e] >= 0.f) ? 4u : 0u) |
                            ((yv[e] >= 0.f) ? 2u : 0u) |
                            ((zv[e] >= 0.f) ? 1u : 0u);
        m |= ((r2 <= 1.0f) && (oc == o)) ? (1u << e) : 0u;
      }
      mbits[j] = m;
      cpk += (unsigned long long)__popc(m) << (16 * j);
    }

    // ---- one packed wave scan (fields <= 2048 < 65536) ----
    unsigned long long inc = cpk;
    #pragma unroll
    for (int d = 1; d < 64; d <<= 1) {
      const unsigned long long t = __shfl_up(inc, (unsigned)d, 64);
      if (lane >= d) inc += t;
    }
    unsigned long long exc = inc - cpk;
    if (lane == 63) sW[k & 1][wid] = inc;
    __syncthreads();  // only barrier per chunk (LDS parity double-buffer)
    unsigned long long tot4 = 0ull;
    #pragma unroll
    for (int w = 0; w < NW; ++w) {
      const unsigned long long v = sW[k & 1][w];
      exc += (w < wid) ? v : 0ull;
      tot4 += v;
    }

    // ---- ordered stores: point order = (round j, tid, elem e) ----
    unsigned racc = 0;
    #pragma unroll
    for (int j = 0; j < NR; ++j) {
      unsigned r = base + racc + (unsigned)((exc >> (16 * j)) & 0xffffull);
      const int g = k * CHUNK + j * (TBLK * 4) + tid * 4;
      const unsigned m = mbits[j];
      #pragma unroll
      for (int e = 0; e < 4; ++e) {
        if (m & (1u << e)) {
          if (r < MAXS) ob[(int)r] = g + e;
          ++r;
        }
      }
      racc += (unsigned)((tot4 >> (16 * j)) & 0xffffull);
    }
    base += racc;                 // uniform across block
    if (base >= MAXS) break;      // my octant is full

    #pragma unroll
    for (int j = 0; j < NR; ++j) {
      curx[j] = nxtx[j]; cury[j] = nxty[j]; curz[j] = nxtz[j];
    }
  }
  #undef LOADR

  // tail: unfilled slots get -1 (no-op when base >= MAXS)
  for (int i = (int)base + tid; i < MAXS; i += TBLK) ob[i] = -1;
}

extern "C" void kernel_launch(void* const* d_in, const int* in_sizes, int n_in,
                              void* d_out, int out_size, void* d_ws, size_t ws_size,
                              hipStream_t stream) {
  const float* pcs = (const float*)d_in[0];
  int* out = (int*)d_out;
  const int B = out_size / (8 * MAXS);   // 16
  const int N = in_sizes[0] / (3 * B);   // 200000
  octant_pf_kernel<<<B * 8, TBLK, 0, stream>>>(pcs, out, N);
}

// Round 11
// 18.771 us; speedup vs baseline: 8.0272x; 1.0761x over previous
//
#include <hip/hip_runtime.h>

#define MAXS 512
#define TBLK 512                 // 8 waves
#define NW (TBLK / 64)
#define NR 4                     // float4 rounds per chunk
#define CHUNK (TBLK * 4 * NR)    // 8192 points per chunk

// One block per (batch, octant); zero cross-block communication (R3/R4/R7:
// device-scope sync costs 50-150us on gfx950). R10 lesson: depth-1 prefetch
// still leaves ~3 serial latency+process legs. Fix: issue ALL loads for the
// first 3 chunks (24576 pts — covers the ~21k fill point; 11-sigma margin)
// at kernel start, then process back-to-back. Residual loop (load->process,
// latency-exposed) keeps the kernel exact for arbitrary inputs.
__global__ __launch_bounds__(TBLK) void octant_pipe3_kernel(
    const float* __restrict__ pcs, int* __restrict__ out, int N) {
  const int blk = blockIdx.x;
  const int b = blk >> 3;
  const unsigned o = (unsigned)(blk & 7);
  const int tid = threadIdx.x, wid = tid >> 6, lane = tid & 63;
  const float* __restrict__ xp = pcs + (size_t)b * 3 * N;
  const float* __restrict__ yp = xp + N;
  const float* __restrict__ zp = yp + N;
  int* __restrict__ ob = out + ((size_t)(b * 8) + o) * MAXS;

  __shared__ unsigned long long sW[2][NW];  // [k parity][wave] packed totals

  const int nCh = (N + CHUNK - 1) / CHUNK;
  unsigned base = 0;  // block-uniform: my octant's filled count

  float4 ax[NR], ay[NR], az[NR];   // stage A (chunk 0 / residual)
  float4 bx[NR], by[NR], bz[NR];   // stage B (chunk 1)
  float4 cx[NR], cy[NR], cz[NR];   // stage C (chunk 2)

  #define LOADR(K, j, DX, DY, DZ)                                     \
    do {                                                              \
      const int _g = (K) * CHUNK + (j) * (TBLK * 4) + tid * 4;        \
      if ((K) < nCh && _g + 4 <= N) {  /* N%4==0 */                   \
        DX = *(const float4*)(xp + _g);                               \
        DY = *(const float4*)(yp + _g);                               \
        DZ = *(const float4*)(zp + _g);                               \
      } else {                                                        \
        DX = make_float4(2.f, 2.f, 2.f, 2.f);  /* sentinel: not in */ \
        DY = DX; DZ = DX;                                             \
      }                                                               \
    } while (0)

  // Classify + rank + scatter one chunk held in registers (SX/SY/SZ).
  // Exactly one barrier; sW slot = k&1 (write[k+2] is after barrier[k+1],
  // which is after read[k] — no race).
  #define PROCESS(SX, SY, SZ, K)                                              \
    do {                                                                      \
      unsigned mbits[NR];                                                     \
      unsigned long long cpk = 0ull; /* u16 per-round counts */               \
      _Pragma("unroll")                                                       \
      for (int j = 0; j < NR; ++j) {                                          \
        float xv[4], yv[4], zv[4];                                            \
        xv[0] = SX[j].x; xv[1] = SX[j].y; xv[2] = SX[j].z; xv[3] = SX[j].w;   \
        yv[0] = SY[j].x; yv[1] = SY[j].y; yv[2] = SY[j].z; yv[3] = SY[j].w;   \
        zv[0] = SZ[j].x; zv[1] = SZ[j].y; zv[2] = SZ[j].z; zv[3] = SZ[j].w;   \
        unsigned m = 0;                                                       \
        _Pragma("unroll")                                                     \
        for (int e = 0; e < 4; ++e) {                                         \
          /* per-op IEEE f32: match numpy exactly at the r2~1 boundary */     \
          const float r2 = __fadd_rn(                                         \
              __fadd_rn(__fmul_rn(xv[e], xv[e]), __fmul_rn(yv[e], yv[e])),    \
              __fmul_rn(zv[e], zv[e]));                                       \
          const unsigned oc = ((xv[e] >= 0.f) ? 4u : 0u) |                    \
                              ((yv[e] >= 0.f) ? 2u : 0u) |                    \
                              ((zv[e] >= 0.f) ? 1u : 0u);                     \
          m |= ((r2 <= 1.0f) && (oc == o)) ? (1u << e) : 0u;                  \
        }                                                                     \
        mbits[j] = m;                                                         \
        cpk += (unsigned long long)__popc(m) << (16 * j);                     \
      }                                                                       \
      unsigned long long inc = cpk; /* wave scan; fields <= 2048 < 65536 */   \
      _Pragma("unroll")                                                       \
      for (int d = 1; d < 64; d <<= 1) {                                      \
        const unsigned long long t = __shfl_up(inc, (unsigned)d, 64);         \
        if (lane >= d) inc += t;                                              \
      }                                                                       \
      unsigned long long exc = inc - cpk;                                     \
      if (lane == 63) sW[(K) & 1][wid] = inc;                                 \
      __syncthreads();                                                        \
      unsigned long long tot4 = 0ull;                                         \
      _Pragma("unroll")                                                       \
      for (int w = 0; w < NW; ++w) {                                          \
        const unsigned long long v = sW[(K) & 1][w];                          \
        exc += (w < wid) ? v : 0ull;                                          \
        tot4 += v;                                                            \
      }                                                                       \
      unsigned racc = 0;                                                      \
      _Pragma("unroll")                                                       \
      for (int j = 0; j < NR; ++j) {                                          \
        unsigned r = base + racc + (unsigned)((exc >> (16 * j)) & 0xffffull); \
        const int g = (K) * CHUNK + j * (TBLK * 4) + tid * 4;                 \
        const unsigned m = mbits[j];                                          \
        _Pragma("unroll")                                                     \
        for (int e = 0; e < 4; ++e) {                                         \
          if (m & (1u << e)) {                                                \
            if (r < MAXS) ob[(int)r] = g + e;                                 \
            ++r;                                                              \
          }                                                                   \
        }                                                                     \
        racc += (unsigned)((tot4 >> (16 * j)) & 0xffffull);                   \
      }                                                                       \
      base += racc; /* uniform */                                             \
    } while (0)

  // ---- issue ALL of chunks 0..2 immediately: full MLP from cycle 0 ----
  #pragma unroll
  for (int j = 0; j < NR; ++j) LOADR(0, j, ax[j], ay[j], az[j]);
  #pragma unroll
  for (int j = 0; j < NR; ++j) LOADR(1, j, bx[j], by[j], bz[j]);
  #pragma unroll
  for (int j = 0; j < NR; ++j) LOADR(2, j, cx[j], cy[j], cz[j]);

  // ---- straight-line processing of the 3 pre-issued chunks ----
  if (0 < nCh && base < MAXS) PROCESS(ax, ay, az, 0);
  if (1 < nCh && base < MAXS) PROCESS(bx, by, bz, 1);
  if (2 < nCh && base < MAXS) PROCESS(cx, cy, cz, 2);

  // ---- residual (exactness path; ~never taken for N(0,1) data) ----
  for (int k = 3; k < nCh && base < MAXS; ++k) {
    #pragma unroll
    for (int j = 0; j < NR; ++j) LOADR(k, j, ax[j], ay[j], az[j]);
    PROCESS(ax, ay, az, k);
  }
  #undef PROCESS
  #undef LOADR

  // tail: unfilled slots get -1 (zero stores when base >= MAXS)
  for (int i = (int)base + tid; i < MAXS; i += TBLK) ob[i] = -1;
}

extern "C" void kernel_launch(void* const* d_in, const int* in_sizes, int n_in,
                              void* d_out, int out_size, void* d_ws, size_t ws_size,
                              hipStream_t stream) {
  const float* pcs = (const float*)d_in[0];
  int* out = (int*)d_out;
  const int B = out_size / (8 * MAXS);   // 16
  const int N = in_sizes[0] / (3 * B);   // 200000
  octant_pipe3_kernel<<<B * 8, TBLK, 0, stream>>>(pcs, out, N);
}

// Round 12
// 15.865 us; speedup vs baseline: 9.4974x; 1.1832x over previous
//
#include <hip/hip_runtime.h>

#define MAXS 512
#define TBLK 1024                // 16 waves, 4/SIMD
#define NWAVE (TBLK / 64)
#define NR 6                     // float4 rounds per window
#define WIN (TBLK * 4 * NR)      // 24576 points: mean 612/octant, 4-sigma > 512

// One block per (batch, octant); zero cross-block communication (R3/R4/R7:
// any device-scope sync costs 50-150us on gfx950). R11 lesson: the 3 serial
// process legs + 3 barriers are the remaining kernel cost -> collapse into
// ONE leg: 1024 threads x 6 float4 rounds = 24576-pt window, single scan,
// single barrier. Residual loop (rare: P ~ 2e-5) preserves exactness.
__global__ __launch_bounds__(TBLK) void octant_onewin_kernel(
    const float* __restrict__ pcs, int* __restrict__ out, int N) {
  const int blk = blockIdx.x;
  const int b = blk >> 3;
  const unsigned o = (unsigned)(blk & 7);
  const int tid = threadIdx.x, wid = tid >> 6, lane = tid & 63;
  const float* __restrict__ xp = pcs + (size_t)b * 3 * N;
  const float* __restrict__ yp = xp + N;
  const float* __restrict__ zp = yp + N;
  int* __restrict__ ob = out + ((size_t)(b * 8) + o) * MAXS;

  __shared__ unsigned long long sW[2][NWAVE][2];  // [leg parity][wave][A/B]

  const int nWin = (N + WIN - 1) / WIN;
  unsigned base = 0;  // block-uniform: my octant's filled count

  float4 ax[NR], ay[NR], az[NR];  // 18 float4 = 72 VGPRs of data

  #define LOADR(W, j)                                                 \
    do {                                                              \
      const int _g = (W) * WIN + (j) * (TBLK * 4) + tid * 4;          \
      if ((W) < nWin && _g + 4 <= N) {  /* N%4==0 */                  \
        ax[j] = *(const float4*)(xp + _g);                            \
        ay[j] = *(const float4*)(yp + _g);                            \
        az[j] = *(const float4*)(zp + _g);                            \
      } else {                                                        \
        ax[j] = make_float4(2.f, 2.f, 2.f, 2.f);  /* sentinel */      \
        ay[j] = ax[j]; az[j] = ax[j];                                 \
      }                                                               \
    } while (0)

  // Classify + rank + scatter the window in registers. ONE barrier; sW
  // parity (K&1) prevents write-after-read races across legs.
  #define PROCESS(K)                                                          \
    do {                                                                      \
      unsigned mbits[NR];                                                     \
      unsigned long long cpkA = 0ull, cpkB = 0ull; /* u16 fields: rounds */   \
      _Pragma("unroll")                                                       \
      for (int j = 0; j < NR; ++j) {                                          \
        float xv[4], yv[4], zv[4];                                            \
        xv[0] = ax[j].x; xv[1] = ax[j].y; xv[2] = ax[j].z; xv[3] = ax[j].w;   \
        yv[0] = ay[j].x; yv[1] = ay[j].y; yv[2] = ay[j].z; yv[3] = ay[j].w;   \
        zv[0] = az[j].x; zv[1] = az[j].y; zv[2] = az[j].z; zv[3] = az[j].w;   \
        unsigned m = 0;                                                       \
        _Pragma("unroll")                                                     \
        for (int e = 0; e < 4; ++e) {                                         \
          /* per-op IEEE f32: match numpy exactly at the r2~1 boundary */     \
          const float r2 = __fadd_rn(                                         \
              __fadd_rn(__fmul_rn(xv[e], xv[e]), __fmul_rn(yv[e], yv[e])),    \
              __fmul_rn(zv[e], zv[e]));                                       \
          const unsigned oc = ((xv[e] >= 0.f) ? 4u : 0u) |                    \
                              ((yv[e] >= 0.f) ? 2u : 0u) |                    \
                              ((zv[e] >= 0.f) ? 1u : 0u);                     \
          m |= ((r2 <= 1.0f) && (oc == o)) ? (1u << e) : 0u;                  \
        }                                                                     \
        mbits[j] = m;                                                         \
        const unsigned long long pc = (unsigned long long)__popc(m);          \
        if (j < 3) cpkA += pc << (16 * j); else cpkB += pc << (16 * (j - 3)); \
      }                                                                       \
      unsigned long long incA = cpkA, incB = cpkB; /* dual packed scan */     \
      _Pragma("unroll")                                                       \
      for (int d = 1; d < 64; d <<= 1) {                                      \
        const unsigned long long tA = __shfl_up(incA, (unsigned)d, 64);       \
        const unsigned long long tB = __shfl_up(incB, (unsigned)d, 64);       \
        if (lane >= d) { incA += tA; incB += tB; }                            \
      }                                                                       \
      unsigned long long excA = incA - cpkA, excB = incB - cpkB;              \
      if (lane == 63) { sW[(K) & 1][wid][0] = incA; sW[(K) & 1][wid][1] = incB; } \
      __syncthreads(); /* the only barrier of the leg */                      \
      unsigned long long totA = 0ull, totB = 0ull;                            \
      _Pragma("unroll")                                                       \
      for (int w = 0; w < NWAVE; ++w) {  /* fields <= 4096 < 65536 */         \
        const unsigned long long vA = sW[(K) & 1][w][0];                      \
        const unsigned long long vB = sW[(K) & 1][w][1];                      \
        excA += (w < wid) ? vA : 0ull;                                        \
        excB += (w < wid) ? vB : 0ull;                                        \
        totA += vA; totB += vB;                                               \
      }                                                                       \
      unsigned racc = 0;                                                      \
      _Pragma("unroll")                                                       \
      for (int j = 0; j < NR; ++j) {                                          \
        const unsigned long long ef = (j < 3) ? excA : excB;                  \
        const unsigned long long tf = (j < 3) ? totA : totB;                  \
        const int sh = 16 * ((j < 3) ? j : (j - 3));                          \
        unsigned r = base + racc + (unsigned)((ef >> sh) & 0xffffull);        \
        const int g = (K) * WIN + j * (TBLK * 4) + tid * 4;                   \
        const unsigned m = mbits[j];                                          \
        _Pragma("unroll")                                                     \
        for (int e = 0; e < 4; ++e) {                                         \
          if (m & (1u << e)) {                                                \
            if (r < MAXS) ob[(int)r] = g + e;                                 \
            ++r;                                                              \
          }                                                                   \
        }                                                                     \
        racc += (unsigned)((tf >> sh) & 0xffffull);                           \
      }                                                                       \
      base += racc; /* block-uniform */                                       \
    } while (0)

  // ---- issue the whole window's 18 loads immediately (full MLP) ----
  #pragma unroll
  for (int j = 0; j < NR; ++j) LOADR(0, j);
  PROCESS(0);

  // ---- residual windows (exactness path; P ~ 2e-5 of being taken) ----
  for (int k = 1; k < nWin && base < MAXS; ++k) {
    #pragma unroll
    for (int j = 0; j < NR; ++j) LOADR(k, j);
    PROCESS(k);
  }
  #undef PROCESS
  #undef LOADR

  // tail: unfilled slots get -1 (zero stores when base >= MAXS)
  for (int i = (int)base + tid; i < MAXS; i += TBLK) ob[i] = -1;
}

extern "C" void kernel_launch(void* const* d_in, const int* in_sizes, int n_in,
                              void* d_out, int out_size, void* d_ws, size_t ws_size,
                              hipStream_t stream) {
  const float* pcs = (const float*)d_in[0];
  int* out = (int*)d_out;
  const int B = out_size / (8 * MAXS);   // 16
  const int N = in_sizes[0] / (3 * B);   // 200000
  octant_onewin_kernel<<<B * 8, TBLK, 0, stream>>>(pcs, out, N);
}